// Round 4
// baseline (470.238 us; speedup 1.0000x reference)
//
#include <hip/hip_runtime.h>
#include <cstdint>
#include <cstddef>

#define B_ 4
#define N_ 8192
#define C_ 128
#define NB_ 256
#define EPS_ 1e-5f

typedef unsigned int u32;
typedef unsigned short u16;

typedef short bf16x8 __attribute__((ext_vector_type(8)));
typedef float f32x4 __attribute__((ext_vector_type(4)));
union U16x8 { uint4 u4; bf16x8 v; };

__device__ __forceinline__ float bf2f(u16 v){ union{u32 i; float f;} x; x.i = ((u32)v)<<16; return x.f; }
__device__ __forceinline__ u16 f2bf(float f){ union{float f; u32 i;} x; x.f=f; u32 r = x.i + 0x7fffu + ((x.i>>16)&1u); return (u16)(r>>16); }
__device__ __forceinline__ u32 pk2(float a, float b){ return (u32)f2bf(a) | ((u32)f2bf(b)<<16); }
__device__ __forceinline__ float sigm(float x){ return 1.f/(1.f+__expf(-x)); }

// ============================ k0w: weight prep ============================
// PW packing (B-fragment order for mfma_f32_16x16x32_bf16):
//   elem index = (((mat*4 + ks)*8 + nt)*64 + lane)*8 + j ;  W[k][n], k = ks*32+(lane>>4)*8+j, n = nt*16+(lane&15)
// mats: 0 Wgq*lnsqw, 1 Wbq*lnsqw, 2 Wgk*lnskw, 3 Wbk*lnskw, 4 Wado, 5 Wq*scale, 6 Wg, 7 Wk, 8 Wv, 9 Wo
// AUX: [0..127] colsum(Wado)
__global__ void k0_prep(const float* __restrict__ Wgq, const float* __restrict__ Wbq,
                        const float* __restrict__ Wgk, const float* __restrict__ Wbk,
                        const float* __restrict__ Wado, const float* __restrict__ Wq_,
                        const float* __restrict__ Wg_, const float* __restrict__ Wk_,
                        const float* __restrict__ Wv_, const float* __restrict__ Wo_,
                        const float* __restrict__ lnsqw, const float* __restrict__ lnskw,
                        u16* __restrict__ PW, float* __restrict__ AUX)
{
  if (blockIdx.x < 80) {
    int gid = blockIdx.x*256 + threadIdx.x;     // 0..20479
    int mat = gid >> 11;
    int rem = gid & 2047;
    int ks = rem >> 9;
    int rem2 = rem & 511;
    int nt = rem2 >> 6;
    int lane = rem2 & 63;
    int kbase = ks*32 + (lane>>4)*8;
    int n = nt*16 + (lane&15);
    const float* W; int scmode = 0; float fixed = 1.f;
    switch (mat) {
      case 0: W = Wgq; scmode = 1; break;
      case 1: W = Wbq; scmode = 1; break;
      case 2: W = Wgk; scmode = 2; break;
      case 3: W = Wbk; scmode = 2; break;
      case 4: W = Wado; break;
      case 5: W = Wq_; fixed = 0.17677669529663687f; break;
      case 6: W = Wg_; break;
      case 7: W = Wk_; break;
      case 8: W = Wv_; break;
      default: W = Wo_; break;
    }
    u16 o[8];
    #pragma unroll
    for (int j=0;j<8;j++){
      int k = kbase + j;
      float sc = fixed;
      if (scmode == 1) sc *= lnsqw[k];
      else if (scmode == 2) sc *= lnskw[k];
      o[j] = f2bf(W[k*128 + n] * sc);
    }
    uint4 pk;
    pk.x = (u32)o[0] | ((u32)o[1]<<16); pk.y = (u32)o[2] | ((u32)o[3]<<16);
    pk.z = (u32)o[4] | ((u32)o[5]<<16); pk.w = (u32)o[6] | ((u32)o[7]<<16);
    *(uint4*)(PW + (size_t)gid*8) = pk;
  } else {
    int t = threadIdx.x;
    if (t < 128) {
      float s = 0.f;
      for (int k=0;k<128;k++) s += Wado[k*128 + t];
      AUX[t] = s;
    }
  }
}

// ============================ MFMA helpers ============================
__device__ __forceinline__ void mm_single(f32x4 acc[4][2], const u16* Abase, const u16* __restrict__ PW,
                                          int mat, int wave, int lane, int lq, int quad)
{
  #pragma unroll
  for (int ks=0; ks<4; ks++){
    U16x8 b0, b1;
    b0.u4 = *(const uint4*)(PW + (size_t)((((mat*4+ks)*8) + wave*2+0)*64 + lane)*8);
    b1.u4 = *(const uint4*)(PW + (size_t)((((mat*4+ks)*8) + wave*2+1)*64 + lane)*8);
    #pragma unroll
    for (int mt=0; mt<4; mt++){
      U16x8 a; a.u4 = *(const uint4*)(Abase + (mt*16+lq)*136 + ks*32 + quad*8);
      acc[mt][0] = __builtin_amdgcn_mfma_f32_16x16x32_bf16(a.v, b0.v, acc[mt][0], 0,0,0);
      acc[mt][1] = __builtin_amdgcn_mfma_f32_16x16x32_bf16(a.v, b1.v, acc[mt][1], 0,0,0);
    }
  }
}
__device__ __forceinline__ void mm_dual(f32x4 acc1[4][2], int m1, f32x4 acc2[4][2], int m2,
                                        const u16* Abase, const u16* __restrict__ PW,
                                        int wave, int lane, int lq, int quad)
{
  #pragma unroll
  for (int ks=0; ks<4; ks++){
    U16x8 b10, b11, b20, b21;
    b10.u4 = *(const uint4*)(PW + (size_t)((((m1*4+ks)*8) + wave*2+0)*64 + lane)*8);
    b11.u4 = *(const uint4*)(PW + (size_t)((((m1*4+ks)*8) + wave*2+1)*64 + lane)*8);
    b20.u4 = *(const uint4*)(PW + (size_t)((((m2*4+ks)*8) + wave*2+0)*64 + lane)*8);
    b21.u4 = *(const uint4*)(PW + (size_t)((((m2*4+ks)*8) + wave*2+1)*64 + lane)*8);
    #pragma unroll
    for (int mt=0; mt<4; mt++){
      U16x8 a; a.u4 = *(const uint4*)(Abase + (mt*16+lq)*136 + ks*32 + quad*8);
      acc1[mt][0] = __builtin_amdgcn_mfma_f32_16x16x32_bf16(a.v, b10.v, acc1[mt][0], 0,0,0);
      acc1[mt][1] = __builtin_amdgcn_mfma_f32_16x16x32_bf16(a.v, b11.v, acc1[mt][1], 0,0,0);
      acc2[mt][0] = __builtin_amdgcn_mfma_f32_16x16x32_bf16(a.v, b20.v, acc2[mt][0], 0,0,0);
      acc2[mt][1] = __builtin_amdgcn_mfma_f32_16x16x32_bf16(a.v, b21.v, acc2[mt][1], 0,0,0);
    }
  }
}
#define ZERO82(A) do{ _Pragma("unroll") for(int _m=0;_m<4;_m++){ A[_m][0]=(f32x4)(0.f); A[_m][1]=(f32x4)(0.f);} }while(0)

// ============================ kf: fused z-bias stream + projection ============================
// grid 1536: blk%3==2 -> projection block (id=blk/3, 0..511); else z-block (id=(blk/3)*2+blk%3, 0..1023).
// Interleaved so HBM-bound z blocks and MFMA-bound proj blocks are co-resident per CU.
//
// z part: one WG per (b,i); reads 256 KB of z in memory order (64 B/lane contiguous),
// LN+Wz+mask-bias -> ZT[4][128][36] bf16 in LDS (pad 36 breaks bank stride), coalesced flush to
// ZB[bi][h][key(128)][q(32)] bf16.
__global__ __launch_bounds__(256, 2)
void kf_fused(const float* __restrict__ ga, const float* __restrict__ gs,
              const float* __restrict__ gz, const float* __restrict__ gmask,
              const float* __restrict__ lnzw, const float* __restrict__ lnzb,
              const float* __restrict__ Wz,
              const float* __restrict__ bgq, const float* __restrict__ bgk,
              const float* __restrict__ bg, const float* __restrict__ bado,
              const u16* __restrict__ PW, const float* __restrict__ AUX,
              u16* __restrict__ Q, u16* __restrict__ K, u16* __restrict__ VT,
              u16* __restrict__ G, u16* __restrict__ ADO, u16* __restrict__ ZB)
{
  __shared__ char arena[52736];
  const int blk = (int)blockIdx.x;
  const int mod = blk % 3;
  const int tid = (int)threadIdx.x;

  if (mod != 2) {
    // ================= z-bias part =================
    u16* ZT   = (u16*)arena;                  // [4][128][36] u16 (36864 B)
    float* WZL = (float*)(arena + 36864);     // [72]
    float* QMV = (float*)(arena + 37152);     // [32]
    float* KMV = (float*)(arena + 37280);     // [128]
    const int bi = (blk/3)*2 + mod;           // 0..1023
    const int b = bi >> 8, i = bi & 255;

    if (tid < 64) WZL[tid] = lnzw[tid>>2] * Wz[tid];
    else if (tid < 68) { int h = tid-64; float s=0.f; for (int c=0;c<16;c++) s += lnzw[c]*Wz[c*4+h]; WZL[64+h]=s; }
    else if (tid < 72) { int h = tid-68; float s=0.f; for (int c=0;c<16;c++) s += lnzb[c]*Wz[c*4+h]; WZL[68+h]=s; }
    else if (tid >= 96 && tid < 128) QMV[tid-96] = gmask[(size_t)b*N_ + i*32 + (tid-96)];
    else if (tid >= 128) {
      int k = tid - 128;
      int raw = i*32 - 48 + k;
      KMV[k] = (raw >= 0 && raw < N_) ? gmask[(size_t)b*N_ + raw] : 0.f;
    }
    __syncthreads();

    #pragma unroll 1
    for (int it=0; it<16; ++it){
      int g = it*256 + tid;                  // linear LN-group index: q = g>>7, key = g&127
      const float* zp = gz + (size_t)bi*65536 + (size_t)g*16;
      float4 z0 = *(const float4*)(zp);
      float4 z1 = *(const float4*)(zp+4);
      float4 z2 = *(const float4*)(zp+8);
      float4 z3 = *(const float4*)(zp+12);
      int q = g >> 7, key = g & 127;
      float zv[16] = {z0.x,z0.y,z0.z,z0.w, z1.x,z1.y,z1.z,z1.w,
                      z2.x,z2.y,z2.z,z2.w, z3.x,z3.y,z3.z,z3.w};
      float sm=0.f, sq=0.f, S0=0.f, S1=0.f, S2=0.f, S3=0.f;
      #pragma unroll
      for (int c=0;c<16;c++){
        sm += zv[c]; sq = fmaf(zv[c],zv[c],sq);
        S0 = fmaf(zv[c], WZL[c*4+0], S0); S1 = fmaf(zv[c], WZL[c*4+1], S1);
        S2 = fmaf(zv[c], WZL[c*4+2], S2); S3 = fmaf(zv[c], WZL[c*4+3], S3);
      }
      float mz = sm*(1.f/16.f);
      float rz = rsqrtf(sq*(1.f/16.f) - mz*mz + EPS_);
      float mb = 1000000000.0f*(QMV[q]*KMV[key] - 1.f);
      int base = key*36 + q;
      ZT[0*4608 + base] = f2bf((S0 - mz*WZL[64])*rz + WZL[68] + mb);
      ZT[1*4608 + base] = f2bf((S1 - mz*WZL[65])*rz + WZL[69] + mb);
      ZT[2*4608 + base] = f2bf((S2 - mz*WZL[66])*rz + WZL[70] + mb);
      ZT[3*4608 + base] = f2bf((S3 - mz*WZL[67])*rz + WZL[71] + mb);
    }
    __syncthreads();

    // coalesced flush: thread t writes out u16 [t*16, t*16+16) of each h-plane
    u16* dst = ZB + (size_t)bi*16384;
    const int key = tid >> 1, q0 = (tid & 1)*16;
    #pragma unroll
    for (int h=0; h<4; h++){
      const u16* src = ZT + h*4608 + key*36 + q0;
      uint2 w0 = *(const uint2*)(src);
      uint2 w1 = *(const uint2*)(src+4);
      uint2 w2 = *(const uint2*)(src+8);
      uint2 w3 = *(const uint2*)(src+12);
      uint4 o0; o0.x=w0.x; o0.y=w0.y; o0.z=w1.x; o0.w=w1.y;
      uint4 o1; o1.x=w2.x; o1.y=w2.y; o1.z=w3.x; o1.w=w3.y;
      *(uint4*)(dst + h*4096 + tid*16)     = o0;
      *(uint4*)(dst + h*4096 + tid*16 + 8) = o1;
    }
    return;
  }

  // ================= projection part =================
  u16* SN  = (u16*)arena;                 // [64][136] sn_hat, later AK
  u16* LNA = (u16*)(arena + 17408);       // [64][136] ln(a)
  u16* AQ  = (u16*)(arena + 34816);       // [64][136]
  float* SSTAT = (float*)(arena + 52224); // [64][2] (mean, std)

  const int rowbase = (blk/3) * 64;
  const int b = rowbase >> 13;
  const int nb0 = rowbase & 8191;
  const int wave = tid >> 6, lane = tid & 63;
  const int lq = lane & 15, quad = lane >> 4;

  {
    const float* sbase = gs + (size_t)rowbase*128;
    const float* abase = ga + (size_t)rowbase*128;
    #pragma unroll 1
    for (int t=0;t<8;t++){
      int chunk = t*256 + tid;
      int row = chunk >> 5;
      int k4 = (chunk & 31) * 4;
      float4 vs = *(const float4*)(sbase + (size_t)chunk*4);
      float4 va = *(const float4*)(abase + (size_t)chunk*4);
      float sm = vs.x+vs.y+vs.z+vs.w, sq = vs.x*vs.x+vs.y*vs.y+vs.z*vs.z+vs.w*vs.w;
      float am = va.x+va.y+va.z+va.w, a2 = va.x*va.x+va.y*va.y+va.z*va.z+va.w*va.w;
      #pragma unroll
      for (int m=1;m<32;m<<=1){
        sm += __shfl_xor(sm,m,32); sq += __shfl_xor(sq,m,32);
        am += __shfl_xor(am,m,32); a2 += __shfl_xor(a2,m,32);
      }
      float smean = sm*(1.f/128.f);
      float svar  = sq*(1.f/128.f) - smean*smean;
      float srstd = rsqrtf(svar + EPS_);
      float amean = am*(1.f/128.f);
      float avar  = a2*(1.f/128.f) - amean*amean;
      float arstd = rsqrtf(avar + EPS_);
      *(uint2*)(SN + row*136 + k4) = make_uint2(
        pk2((vs.x-smean)*srstd,(vs.y-smean)*srstd), pk2((vs.z-smean)*srstd,(vs.w-smean)*srstd));
      *(uint2*)(LNA + row*136 + k4) = make_uint2(
        pk2((va.x-amean)*arstd,(va.y-amean)*arstd), pk2((va.z-amean)*arstd,(va.w-amean)*arstd));
      if ((tid & 31) == 0){
        SSTAT[row*2]   = smean;
        SSTAT[row*2+1] = (svar + EPS_)*srstd;   // sqrt(var+eps)
      }
    }
  }
  __syncthreads();

  const int cg0 = wave*32 + lq;
  const int cg1 = cg0 + 16;

  // ADO
  {
    f32x4 acc[4][2]; ZERO82(acc);
    mm_single(acc, SN, PW, 4, wave, lane, lq, quad);
    float cs0 = AUX[cg0], cs1 = AUX[cg1];
    float bb0 = bado[cg0], bb1 = bado[cg1];
    #pragma unroll
    for (int mt=0; mt<4; mt++){
      #pragma unroll
      for (int reg=0; reg<4; reg++){
        int row = mt*16 + quad*4 + reg;
        float mean = SSTAT[row*2], std = SSTAT[row*2+1];
        ADO[(size_t)(rowbase+row)*128 + cg0] = f2bf(sigm(std*acc[mt][0][reg] + mean*cs0 + bb0));
        ADO[(size_t)(rowbase+row)*128 + cg1] = f2bf(sigm(std*acc[mt][1][reg] + mean*cs1 + bb1));
      }
    }
  }

  // AQ
  {
    f32x4 aG[4][2], aB[4][2]; ZERO82(aG); ZERO82(aB);
    mm_dual(aG, 0, aB, 1, SN, PW, wave, lane, lq, quad);
    float bq0 = bgq[cg0], bq1 = bgq[cg1];
    #pragma unroll
    for (int mt=0; mt<4; mt++){
      #pragma unroll
      for (int reg=0; reg<4; reg++){
        int row = mt*16 + quad*4 + reg;
        float l0 = bf2f(LNA[row*136 + cg0]), l1 = bf2f(LNA[row*136 + cg1]);
        AQ[row*136 + cg0] = f2bf(sigm(aG[mt][0][reg]+bq0)*l0 + aB[mt][0][reg]);
        AQ[row*136 + cg1] = f2bf(sigm(aG[mt][1][reg]+bq1)*l1 + aB[mt][1][reg]);
      }
    }
  }

  // AK (into SN)
  {
    f32x4 aG[4][2], aB[4][2]; ZERO82(aG); ZERO82(aB);
    mm_dual(aG, 2, aB, 3, SN, PW, wave, lane, lq, quad);
    float bk0 = bgk[cg0], bk1 = bgk[cg1];
    #pragma unroll
    for (int mt=0; mt<4; mt++){
      #pragma unroll
      for (int reg=0; reg<4; reg++){
        int row = mt*16 + quad*4 + reg;
        float l0 = bf2f(LNA[row*136 + cg0]), l1 = bf2f(LNA[row*136 + cg1]);
        aG[mt][0][reg] = sigm(aG[mt][0][reg]+bk0)*l0 + aB[mt][0][reg];
        aG[mt][1][reg] = sigm(aG[mt][1][reg]+bk1)*l1 + aB[mt][1][reg];
      }
    }
    __syncthreads();
    #pragma unroll
    for (int mt=0; mt<4; mt++){
      #pragma unroll
      for (int reg=0; reg<4; reg++){
        int row = mt*16 + quad*4 + reg;
        SN[row*136 + cg0] = f2bf(aG[mt][0][reg]);
        SN[row*136 + cg1] = f2bf(aG[mt][1][reg]);
      }
    }
    __syncthreads();
  }

  // Q + G (row-major)
  {
    f32x4 aQ_[4][2], aG_[4][2]; ZERO82(aQ_); ZERO82(aG_);
    mm_dual(aQ_, 5, aG_, 6, AQ, PW, wave, lane, lq, quad);
    float bg0 = bg[cg0], bg1 = bg[cg1];
    #pragma unroll
    for (int mt=0; mt<4; mt++){
      #pragma unroll
      for (int reg=0; reg<4; reg++){
        int row = mt*16 + quad*4 + reg;
        Q[(size_t)(rowbase+row)*128 + cg0] = f2bf(aQ_[mt][0][reg]);
        Q[(size_t)(rowbase+row)*128 + cg1] = f2bf(aQ_[mt][1][reg]);
        G[(size_t)(rowbase+row)*128 + cg0] = f2bf(sigm(aG_[mt][0][reg]+bg0));
        G[(size_t)(rowbase+row)*128 + cg1] = f2bf(sigm(aG_[mt][1][reg]+bg1));
      }
    }
  }

  // K (row-major) + VT (transposed)
  {
    f32x4 aK_[4][2], aV_[4][2]; ZERO82(aK_); ZERO82(aV_);
    mm_dual(aK_, 7, aV_, 8, SN, PW, wave, lane, lq, quad);
    #pragma unroll
    for (int mt=0; mt<4; mt++){
      #pragma unroll
      for (int reg=0; reg<4; reg++){
        int row = mt*16 + quad*4 + reg;
        K[(size_t)(rowbase+row)*128 + cg0] = f2bf(aK_[mt][0][reg]);
        K[(size_t)(rowbase+row)*128 + cg1] = f2bf(aK_[mt][1][reg]);
      }
      ushort4 p0, p1;
      p0.x = f2bf(aV_[mt][0][0]); p0.y = f2bf(aV_[mt][0][1]);
      p0.z = f2bf(aV_[mt][0][2]); p0.w = f2bf(aV_[mt][0][3]);
      p1.x = f2bf(aV_[mt][1][0]); p1.y = f2bf(aV_[mt][1][1]);
      p1.z = f2bf(aV_[mt][1][2]); p1.w = f2bf(aV_[mt][1][3]);
      int nloc = nb0 + mt*16 + quad*4;
      *(ushort4*)(VT + ((size_t)(b*128 + cg0))*N_ + nloc) = p0;
      *(ushort4*)(VT + ((size_t)(b*128 + cg1))*N_ + nloc) = p1;
    }
  }
}

// ============================ k2: windowed attention ============================
// 1D grid 1024: flat&7 -> XCD-contiguous window span; wave h owns head h.
__global__ __launch_bounds__(256, 4)
void k2_attn(const float* __restrict__ bo,
             const u16* __restrict__ PW,
             const u16* __restrict__ Q, const u16* __restrict__ K,
             const u16* __restrict__ VT, const u16* __restrict__ G,
             const u16* __restrict__ ADO, const u16* __restrict__ ZB,
             float* __restrict__ gout)
{
  __shared__ char arena[34816];
  u16* ATTall = (u16*)arena;       // 4 x [32][136] bf16 per-wave
  u16* GO     = (u16*)arena;       // [32][136] bf16, aliases ATT after barrier

  const int flat = (int)blockIdx.x;
  const int x = flat & 7, r = flat >> 3;
  const int j = r & 31, b = r >> 5;
  const int i = x*32 + j;

  const int tid = (int)threadIdx.x;
  const int wave = tid >> 6, lane = tid & 63;
  const int lq = lane & 15, quad = lane >> 4;
  const int h = wave;
  const int start = i*32 - 48;
  u16* ATT = ATTall + h*(32*136);

  // -------- logits: L = Q_h @ K_h^T --------
  f32x4 L[2][8];
  #pragma unroll
  for (int mt=0;mt<2;mt++) for (int nt=0;nt<8;nt++) L[mt][nt] = (f32x4)(0.f);
  {
    U16x8 aQ[2];
    #pragma unroll
    for (int mt=0;mt<2;mt++)
      aQ[mt].u4 = *(const uint4*)(Q + ((size_t)b*N_ + i*32 + mt*16 + lq)*128 + h*32 + quad*8);
    #pragma unroll
    for (int nt=0;nt<8;nt++){
      int kr = min(max(start + nt*16 + lq, 0), N_-1);
      U16x8 bk; bk.u4 = *(const uint4*)(K + ((size_t)b*N_ + kr)*128 + h*32 + quad*8);
      L[0][nt] = __builtin_amdgcn_mfma_f32_16x16x32_bf16(aQ[0].v, bk.v, L[0][nt], 0,0,0);
      L[1][nt] = __builtin_amdgcn_mfma_f32_16x16x32_bf16(aQ[1].v, bk.v, L[1][nt], 0,0,0);
    }
  }

  // -------- add precomputed bias (pair + mask) --------
  {
    const u16* zbb = ZB + (size_t)(b*NB_ + i)*16384 + h*4096;
    #pragma unroll
    for (int nt=0;nt<8;nt++){
      #pragma unroll
      for (int mt=0;mt<2;mt++){
        ushort4 z4 = *(const ushort4*)(zbb + (nt*16+lq)*32 + mt*16 + quad*4);
        L[mt][nt][0] += bf2f(z4.x); L[mt][nt][1] += bf2f(z4.y);
        L[mt][nt][2] += bf2f(z4.z); L[mt][nt][3] += bf2f(z4.w);
      }
    }
  }

  // -------- softmax, write attn bf16 into per-wave ATT --------
  #pragma unroll
  for (int mt=0;mt<2;mt++){
    #pragma unroll
    for (int reg=0;reg<4;reg++){
      float mx = -3.0e38f;
      #pragma unroll
      for (int nt=0;nt<8;nt++) mx = fmaxf(mx, L[mt][nt][reg]);
      mx = fmaxf(mx, __shfl_xor(mx,1,16));
      mx = fmaxf(mx, __shfl_xor(mx,2,16));
      mx = fmaxf(mx, __shfl_xor(mx,4,16));
      mx = fmaxf(mx, __shfl_xor(mx,8,16));
      float e[8]; float s = 0.f;
      #pragma unroll
      for (int nt=0;nt<8;nt++){ e[nt] = __expf(L[mt][nt][reg]-mx); s += e[nt]; }
      s += __shfl_xor(s,1,16);
      s += __shfl_xor(s,2,16);
      s += __shfl_xor(s,4,16);
      s += __shfl_xor(s,8,16);
      float inv = 1.f/s;
      int q = mt*16 + quad*4 + reg;
      #pragma unroll
      for (int nt=0;nt<8;nt++) ATT[q*136 + nt*16 + lq] = f2bf(e[nt]*inv);
    }
  }

  // -------- o^T = V_h^T @ attn^T --------
  f32x4 O[2][2];
  O[0][0]=(f32x4)(0.f); O[0][1]=(f32x4)(0.f); O[1][0]=(f32x4)(0.f); O[1][1]=(f32x4)(0.f);
  #pragma unroll
  for (int ks=0;ks<4;ks++){
    U16x8 ba[2];
    #pragma unroll
    for (int nt=0;nt<2;nt++)
      ba[nt].u4 = *(const uint4*)(ATT + (nt*16+lq)*136 + ks*32 + quad*8);
    int kk = start + ks*32 + quad*8;
    kk = min(max(kk,0), N_-8);
    #pragma unroll
    for (int mt=0;mt<2;mt++){
      U16x8 av;
      av.u4 = *(const uint4*)(VT + ((size_t)(b*128 + h*32 + mt*16 + lq))*N_ + kk);
      O[mt][0] = __builtin_amdgcn_mfma_f32_16x16x32_bf16(av.v, ba[0].v, O[mt][0], 0,0,0);
      O[mt][1] = __builtin_amdgcn_mfma_f32_16x16x32_bf16(av.v, ba[1].v, O[mt][1], 0,0,0);
    }
  }
  __syncthreads();   // all waves done reading ATT before GO overwrites arena

  // -------- gate (row-major G), write g*o into GO --------
  #pragma unroll
  for (int mt=0;mt<2;mt++){
    #pragma unroll
    for (int nt=0;nt<2;nt++){
      int q = nt*16 + lq;
      int cb = h*32 + mt*16 + quad*4;
      ushort4 g4 = *(const ushort4*)(G + ((size_t)b*N_ + i*32 + q)*128 + cb);
      ushort4 p;
      p.x = f2bf(bf2f(g4.x)*O[mt][nt][0]); p.y = f2bf(bf2f(g4.y)*O[mt][nt][1]);
      p.z = f2bf(bf2f(g4.z)*O[mt][nt][2]); p.w = f2bf(bf2f(g4.w)*O[mt][nt][3]);
      *(ushort4*)(GO + q*136 + cb) = p;
    }
  }
  __syncthreads();

  // -------- out = sigmoid(ado) * (GO @ Wo + bo) --------
  {
    f32x4 U[2][2];
    U[0][0]=(f32x4)(0.f); U[0][1]=(f32x4)(0.f); U[1][0]=(f32x4)(0.f); U[1][1]=(f32x4)(0.f);
    #pragma unroll
    for (int ks=0;ks<4;ks++){
      U16x8 b0, b1;
      b0.u4 = *(const uint4*)(PW + (size_t)((((9*4+ks)*8) + wave*2+0)*64 + lane)*8);
      b1.u4 = *(const uint4*)(PW + (size_t)((((9*4+ks)*8) + wave*2+1)*64 + lane)*8);
      #pragma unroll
      for (int mt=0;mt<2;mt++){
        U16x8 a; a.u4 = *(const uint4*)(GO + (mt*16+lq)*136 + ks*32 + quad*8);
        U[mt][0] = __builtin_amdgcn_mfma_f32_16x16x32_bf16(a.v, b0.v, U[mt][0], 0,0,0);
        U[mt][1] = __builtin_amdgcn_mfma_f32_16x16x32_bf16(a.v, b1.v, U[mt][1], 0,0,0);
      }
    }
    const int cg0 = wave*32 + lq, cg1 = cg0 + 16;
    float b00 = bo[cg0], b01 = bo[cg1];
    #pragma unroll
    for (int mt=0;mt<2;mt++){
      #pragma unroll
      for (int reg=0;reg<4;reg++){
        int q = mt*16 + quad*4 + reg;
        size_t rowoff = ((size_t)b*N_ + i*32 + q)*128;
        float ad0 = bf2f(ADO[rowoff + cg0]);
        float ad1 = bf2f(ADO[rowoff + cg1]);
        gout[rowoff + cg0] = ad0*(U[mt][0][reg] + b00);
        gout[rowoff + cg1] = ad1*(U[mt][1][reg] + b01);
      }
    }
  }
}

// ============================ launch ============================
extern "C" void kernel_launch(void* const* d_in, const int* in_sizes, int n_in,
                              void* d_out, int out_size, void* d_ws, size_t ws_size,
                              hipStream_t stream) {
  (void)in_sizes; (void)n_in; (void)out_size; (void)ws_size;
  const float* ga    = (const float*)d_in[0];
  const float* gz    = (const float*)d_in[1];
  const float* gs    = (const float*)d_in[2];
  const float* gmask = (const float*)d_in[3];
  const float* lnsqw = (const float*)d_in[4];
  const float* Wgq   = (const float*)d_in[5];
  const float* bgq   = (const float*)d_in[6];
  const float* Wbq   = (const float*)d_in[7];
  const float* lnskw = (const float*)d_in[8];
  const float* Wgk   = (const float*)d_in[9];
  const float* bgk   = (const float*)d_in[10];
  const float* Wbk   = (const float*)d_in[11];
  const float* lnzw  = (const float*)d_in[12];
  const float* lnzb  = (const float*)d_in[13];
  const float* Wz    = (const float*)d_in[14];
  const float* Wq    = (const float*)d_in[15];
  const float* Wk    = (const float*)d_in[16];
  const float* Wv    = (const float*)d_in[17];
  const float* Wg    = (const float*)d_in[18];
  const float* bg    = (const float*)d_in[19];
  const float* Wo    = (const float*)d_in[20];
  const float* bo    = (const float*)d_in[21];
  const float* Wado  = (const float*)d_in[22];
  const float* bado  = (const float*)d_in[23];

  char* ws = (char*)d_ws;
  u16* Qb  = (u16*)(ws + 0);
  u16* Kb  = (u16*)(ws + 8388608);
  u16* VTb = (u16*)(ws + 16777216);
  u16* Gb  = (u16*)(ws + 25165824);
  u16* ADOb= (u16*)(ws + 33554432);
  u16* ZBb = (u16*)(ws + 41943040);
  u16* PW  = (u16*)(ws + 75497472);
  float* AUX = (float*)(ws + 75497472 + 327680);

  k0_prep<<<81, 256, 0, stream>>>(Wgq, Wbq, Wgk, Wbk, Wado, Wq, Wg, Wk, Wv, Wo,
                                  lnsqw, lnskw, PW, AUX);
  kf_fused<<<1536, 256, 0, stream>>>(ga, gs, gz, gmask, lnzw, lnzb, Wz,
                                     bgq, bgk, bg, bado, PW, AUX,
                                     Qb, Kb, VTb, Gb, ADOb, ZBb);
  k2_attn<<<1024, 256, 0, stream>>>(bo, PW, Qb, Kb, VTb, Gb, ADOb, ZBb, (float*)d_out);
}

// Round 5
// 462.156 us; speedup vs baseline: 1.0175x; 1.0175x over previous
//
#include <hip/hip_runtime.h>
#include <cstdint>
#include <cstddef>

#define B_ 4
#define N_ 8192
#define C_ 128
#define NB_ 256
#define EPS_ 1e-5f

typedef unsigned int u32;
typedef unsigned short u16;

typedef short bf16x8 __attribute__((ext_vector_type(8)));
typedef float f32x4 __attribute__((ext_vector_type(4)));
union U16x8 { uint4 u4; bf16x8 v; };

__device__ __forceinline__ float bf2f(u16 v){ union{u32 i; float f;} x; x.i = ((u32)v)<<16; return x.f; }
__device__ __forceinline__ u16 f2bf(float f){ union{float f; u32 i;} x; x.f=f; u32 r = x.i + 0x7fffu + ((x.i>>16)&1u); return (u16)(r>>16); }
__device__ __forceinline__ u32 pk2(float a, float b){ return (u32)f2bf(a) | ((u32)f2bf(b)<<16); }
__device__ __forceinline__ float sigm(float x){ return 1.f/(1.f+__expf(-x)); }

// ============================ k0: weight prep ============================
// PW packing (B-fragment order for mfma_f32_16x16x32_bf16):
//   elem index = (((mat*4 + ks)*8 + nt)*64 + lane)*8 + j ;  W[k][n], k = ks*32+(lane>>4)*8+j, n = nt*16+(lane&15)
// mats: 0 Wgq*lnsqw, 1 Wbq*lnsqw, 2 Wgk*lnskw, 3 Wbk*lnskw, 4 Wado, 5 Wq*scale, 6 Wg, 7 Wk, 8 Wv, 9 Wo
// AUX: [0..127] colsum(Wado)
__global__ void k0_prep(const float* __restrict__ Wgq, const float* __restrict__ Wbq,
                        const float* __restrict__ Wgk, const float* __restrict__ Wbk,
                        const float* __restrict__ Wado, const float* __restrict__ Wq_,
                        const float* __restrict__ Wg_, const float* __restrict__ Wk_,
                        const float* __restrict__ Wv_, const float* __restrict__ Wo_,
                        const float* __restrict__ lnsqw, const float* __restrict__ lnskw,
                        u16* __restrict__ PW, float* __restrict__ AUX)
{
  if (blockIdx.x < 80) {
    int gid = blockIdx.x*256 + threadIdx.x;     // 0..20479
    int mat = gid >> 11;
    int rem = gid & 2047;
    int ks = rem >> 9;
    int rem2 = rem & 511;
    int nt = rem2 >> 6;
    int lane = rem2 & 63;
    int kbase = ks*32 + (lane>>4)*8;
    int n = nt*16 + (lane&15);
    const float* W; int scmode = 0; float fixed = 1.f;
    switch (mat) {
      case 0: W = Wgq; scmode = 1; break;
      case 1: W = Wbq; scmode = 1; break;
      case 2: W = Wgk; scmode = 2; break;
      case 3: W = Wbk; scmode = 2; break;
      case 4: W = Wado; break;
      case 5: W = Wq_; fixed = 0.17677669529663687f; break;
      case 6: W = Wg_; break;
      case 7: W = Wk_; break;
      case 8: W = Wv_; break;
      default: W = Wo_; break;
    }
    u16 o[8];
    #pragma unroll
    for (int j=0;j<8;j++){
      int k = kbase + j;
      float sc = fixed;
      if (scmode == 1) sc *= lnsqw[k];
      else if (scmode == 2) sc *= lnskw[k];
      o[j] = f2bf(W[k*128 + n] * sc);
    }
    uint4 pk;
    pk.x = (u32)o[0] | ((u32)o[1]<<16); pk.y = (u32)o[2] | ((u32)o[3]<<16);
    pk.z = (u32)o[4] | ((u32)o[5]<<16); pk.w = (u32)o[6] | ((u32)o[7]<<16);
    *(uint4*)(PW + (size_t)gid*8) = pk;
  } else {
    int t = threadIdx.x;
    if (t < 128) {
      float s = 0.f;
      for (int k=0;k<128;k++) s += Wado[k*128 + t];
      AUX[t] = s;
    }
  }
}

// ============================ MFMA helpers ============================
__device__ __forceinline__ void mm_single(f32x4 acc[4][2], const u16* Abase, const u16* __restrict__ PW,
                                          int mat, int wave, int lane, int lq, int quad)
{
  #pragma unroll
  for (int ks=0; ks<4; ks++){
    U16x8 b0, b1;
    b0.u4 = *(const uint4*)(PW + (size_t)((((mat*4+ks)*8) + wave*2+0)*64 + lane)*8);
    b1.u4 = *(const uint4*)(PW + (size_t)((((mat*4+ks)*8) + wave*2+1)*64 + lane)*8);
    #pragma unroll
    for (int mt=0; mt<4; mt++){
      U16x8 a; a.u4 = *(const uint4*)(Abase + (mt*16+lq)*136 + ks*32 + quad*8);
      acc[mt][0] = __builtin_amdgcn_mfma_f32_16x16x32_bf16(a.v, b0.v, acc[mt][0], 0,0,0);
      acc[mt][1] = __builtin_amdgcn_mfma_f32_16x16x32_bf16(a.v, b1.v, acc[mt][1], 0,0,0);
    }
  }
}
__device__ __forceinline__ void mm_dual(f32x4 acc1[4][2], int m1, f32x4 acc2[4][2], int m2,
                                        const u16* Abase, const u16* __restrict__ PW,
                                        int wave, int lane, int lq, int quad)
{
  #pragma unroll
  for (int ks=0; ks<4; ks++){
    U16x8 b10, b11, b20, b21;
    b10.u4 = *(const uint4*)(PW + (size_t)((((m1*4+ks)*8) + wave*2+0)*64 + lane)*8);
    b11.u4 = *(const uint4*)(PW + (size_t)((((m1*4+ks)*8) + wave*2+1)*64 + lane)*8);
    b20.u4 = *(const uint4*)(PW + (size_t)((((m2*4+ks)*8) + wave*2+0)*64 + lane)*8);
    b21.u4 = *(const uint4*)(PW + (size_t)((((m2*4+ks)*8) + wave*2+1)*64 + lane)*8);
    #pragma unroll
    for (int mt=0; mt<4; mt++){
      U16x8 a; a.u4 = *(const uint4*)(Abase + (mt*16+lq)*136 + ks*32 + quad*8);
      acc1[mt][0] = __builtin_amdgcn_mfma_f32_16x16x32_bf16(a.v, b10.v, acc1[mt][0], 0,0,0);
      acc1[mt][1] = __builtin_amdgcn_mfma_f32_16x16x32_bf16(a.v, b11.v, acc1[mt][1], 0,0,0);
      acc2[mt][0] = __builtin_amdgcn_mfma_f32_16x16x32_bf16(a.v, b20.v, acc2[mt][0], 0,0,0);
      acc2[mt][1] = __builtin_amdgcn_mfma_f32_16x16x32_bf16(a.v, b21.v, acc2[mt][1], 0,0,0);
    }
  }
}
#define ZERO82(A) do{ _Pragma("unroll") for(int _m=0;_m<4;_m++){ A[_m][0]=(f32x4)(0.f); A[_m][1]=(f32x4)(0.f);} }while(0)

// ============================ k1: LN + 9-way projection GEMM ============================
// 64 rows per WG, 512 WGs. Q,K,G,ADO row-major [B*N][128] bf16; VT [B][128][N] bf16.
__global__ __launch_bounds__(256, 2)
void k1_proj(const float* __restrict__ ga, const float* __restrict__ gs,
             const float* __restrict__ bgq, const float* __restrict__ bgk,
             const float* __restrict__ bg, const float* __restrict__ bado,
             const u16* __restrict__ PW, const float* __restrict__ AUX,
             u16* __restrict__ Q, u16* __restrict__ K, u16* __restrict__ VT,
             u16* __restrict__ G, u16* __restrict__ ADO)
{
  __shared__ char arena[52736];
  u16* SN  = (u16*)arena;                 // [64][136] sn_hat, later AK
  u16* LNA = (u16*)(arena + 17408);       // [64][136] ln(a)
  u16* AQ  = (u16*)(arena + 34816);       // [64][136]
  float* SSTAT = (float*)(arena + 52224); // [64][2] (mean, std)

  const int tid = (int)threadIdx.x;
  const int rowbase = (int)blockIdx.x * 64;
  const int b = rowbase >> 13;
  const int nb0 = rowbase & 8191;
  const int wave = tid >> 6, lane = tid & 63;
  const int lq = lane & 15, quad = lane >> 4;

  {
    const float* sbase = gs + (size_t)rowbase*128;
    const float* abase = ga + (size_t)rowbase*128;
    #pragma unroll 1
    for (int t=0;t<8;t++){
      int chunk = t*256 + tid;
      int row = chunk >> 5;
      int k4 = (chunk & 31) * 4;
      float4 vs = *(const float4*)(sbase + (size_t)chunk*4);
      float4 va = *(const float4*)(abase + (size_t)chunk*4);
      float sm = vs.x+vs.y+vs.z+vs.w, sq = vs.x*vs.x+vs.y*vs.y+vs.z*vs.z+vs.w*vs.w;
      float am = va.x+va.y+va.z+va.w, a2 = va.x*va.x+va.y*va.y+va.z*va.z+va.w*va.w;
      #pragma unroll
      for (int m=1;m<32;m<<=1){
        sm += __shfl_xor(sm,m,32); sq += __shfl_xor(sq,m,32);
        am += __shfl_xor(am,m,32); a2 += __shfl_xor(a2,m,32);
      }
      float smean = sm*(1.f/128.f);
      float svar  = sq*(1.f/128.f) - smean*smean;
      float srstd = rsqrtf(svar + EPS_);
      float amean = am*(1.f/128.f);
      float avar  = a2*(1.f/128.f) - amean*amean;
      float arstd = rsqrtf(avar + EPS_);
      *(uint2*)(SN + row*136 + k4) = make_uint2(
        pk2((vs.x-smean)*srstd,(vs.y-smean)*srstd), pk2((vs.z-smean)*srstd,(vs.w-smean)*srstd));
      *(uint2*)(LNA + row*136 + k4) = make_uint2(
        pk2((va.x-amean)*arstd,(va.y-amean)*arstd), pk2((va.z-amean)*arstd,(va.w-amean)*arstd));
      if ((tid & 31) == 0){
        SSTAT[row*2]   = smean;
        SSTAT[row*2+1] = (svar + EPS_)*srstd;   // sqrt(var+eps)
      }
    }
  }
  __syncthreads();

  const int cg0 = wave*32 + lq;
  const int cg1 = cg0 + 16;

  // ADO
  {
    f32x4 acc[4][2]; ZERO82(acc);
    mm_single(acc, SN, PW, 4, wave, lane, lq, quad);
    float cs0 = AUX[cg0], cs1 = AUX[cg1];
    float bb0 = bado[cg0], bb1 = bado[cg1];
    #pragma unroll
    for (int mt=0; mt<4; mt++){
      #pragma unroll
      for (int reg=0; reg<4; reg++){
        int row = mt*16 + quad*4 + reg;
        float mean = SSTAT[row*2], std = SSTAT[row*2+1];
        ADO[(size_t)(rowbase+row)*128 + cg0] = f2bf(sigm(std*acc[mt][0][reg] + mean*cs0 + bb0));
        ADO[(size_t)(rowbase+row)*128 + cg1] = f2bf(sigm(std*acc[mt][1][reg] + mean*cs1 + bb1));
      }
    }
  }

  // AQ
  {
    f32x4 aG[4][2], aB[4][2]; ZERO82(aG); ZERO82(aB);
    mm_dual(aG, 0, aB, 1, SN, PW, wave, lane, lq, quad);
    float bq0 = bgq[cg0], bq1 = bgq[cg1];
    #pragma unroll
    for (int mt=0; mt<4; mt++){
      #pragma unroll
      for (int reg=0; reg<4; reg++){
        int row = mt*16 + quad*4 + reg;
        float l0 = bf2f(LNA[row*136 + cg0]), l1 = bf2f(LNA[row*136 + cg1]);
        AQ[row*136 + cg0] = f2bf(sigm(aG[mt][0][reg]+bq0)*l0 + aB[mt][0][reg]);
        AQ[row*136 + cg1] = f2bf(sigm(aG[mt][1][reg]+bq1)*l1 + aB[mt][1][reg]);
      }
    }
  }

  // AK (into SN)
  {
    f32x4 aG[4][2], aB[4][2]; ZERO82(aG); ZERO82(aB);
    mm_dual(aG, 2, aB, 3, SN, PW, wave, lane, lq, quad);
    float bk0 = bgk[cg0], bk1 = bgk[cg1];
    #pragma unroll
    for (int mt=0; mt<4; mt++){
      #pragma unroll
      for (int reg=0; reg<4; reg++){
        int row = mt*16 + quad*4 + reg;
        float l0 = bf2f(LNA[row*136 + cg0]), l1 = bf2f(LNA[row*136 + cg1]);
        aG[mt][0][reg] = sigm(aG[mt][0][reg]+bk0)*l0 + aB[mt][0][reg];
        aG[mt][1][reg] = sigm(aG[mt][1][reg]+bk1)*l1 + aB[mt][1][reg];
      }
    }
    __syncthreads();
    #pragma unroll
    for (int mt=0; mt<4; mt++){
      #pragma unroll
      for (int reg=0; reg<4; reg++){
        int row = mt*16 + quad*4 + reg;
        SN[row*136 + cg0] = f2bf(aG[mt][0][reg]);
        SN[row*136 + cg1] = f2bf(aG[mt][1][reg]);
      }
    }
    __syncthreads();
  }

  // Q + G (row-major)
  {
    f32x4 aQ_[4][2], aG_[4][2]; ZERO82(aQ_); ZERO82(aG_);
    mm_dual(aQ_, 5, aG_, 6, AQ, PW, wave, lane, lq, quad);
    float bg0 = bg[cg0], bg1 = bg[cg1];
    #pragma unroll
    for (int mt=0; mt<4; mt++){
      #pragma unroll
      for (int reg=0; reg<4; reg++){
        int row = mt*16 + quad*4 + reg;
        Q[(size_t)(rowbase+row)*128 + cg0] = f2bf(aQ_[mt][0][reg]);
        Q[(size_t)(rowbase+row)*128 + cg1] = f2bf(aQ_[mt][1][reg]);
        G[(size_t)(rowbase+row)*128 + cg0] = f2bf(sigm(aG_[mt][0][reg]+bg0));
        G[(size_t)(rowbase+row)*128 + cg1] = f2bf(sigm(aG_[mt][1][reg]+bg1));
      }
    }
  }

  // K (row-major) + VT (transposed)
  {
    f32x4 aK_[4][2], aV_[4][2]; ZERO82(aK_); ZERO82(aV_);
    mm_dual(aK_, 7, aV_, 8, SN, PW, wave, lane, lq, quad);
    #pragma unroll
    for (int mt=0; mt<4; mt++){
      #pragma unroll
      for (int reg=0; reg<4; reg++){
        int row = mt*16 + quad*4 + reg;
        K[(size_t)(rowbase+row)*128 + cg0] = f2bf(aK_[mt][0][reg]);
        K[(size_t)(rowbase+row)*128 + cg1] = f2bf(aK_[mt][1][reg]);
      }
      ushort4 p0, p1;
      p0.x = f2bf(aV_[mt][0][0]); p0.y = f2bf(aV_[mt][0][1]);
      p0.z = f2bf(aV_[mt][0][2]); p0.w = f2bf(aV_[mt][0][3]);
      p1.x = f2bf(aV_[mt][1][0]); p1.y = f2bf(aV_[mt][1][1]);
      p1.z = f2bf(aV_[mt][1][2]); p1.w = f2bf(aV_[mt][1][3]);
      int nloc = nb0 + mt*16 + quad*4;
      *(ushort4*)(VT + ((size_t)(b*128 + cg0))*N_ + nloc) = p0;
      *(ushort4*)(VT + ((size_t)(b*128 + cg1))*N_ + nloc) = p1;
    }
  }
}

// ============================ k2: z-bias + windowed attention (fused) ============================
// 1D grid 1024: flat&7 -> XCD-contiguous window span; wave h owns head h.
// Phase Z: stream this window's 256 KB of z coalesced, LN+Wz+mask-bias -> ZT[4][128][36] bf16 in LDS.
// Then QK^T (MFMA) + bias add (ushort4 LDS reads) + softmax + PV + gated epilogue.
__global__ __launch_bounds__(256, 4)
void k2_attn(const float* __restrict__ gz, const float* __restrict__ gmask,
             const float* __restrict__ lnzw, const float* __restrict__ lnzb,
             const float* __restrict__ Wz, const float* __restrict__ bo,
             const u16* __restrict__ PW,
             const u16* __restrict__ Q, const u16* __restrict__ K,
             const u16* __restrict__ VT, const u16* __restrict__ G,
             const u16* __restrict__ ADO, float* __restrict__ gout)
{
  __shared__ char arena[37888];
  u16* ZT     = (u16*)arena;             // [4][128][36] u16 = 36864 B (plane h at h*4608 elems)
  u16* ATTall = (u16*)arena;             // wave h: [32][136] at h*8704 B (aliases ZT after barrier)
  u16* GO     = (u16*)arena;             // [32][136] (aliases ATT after barrier)
  float* WZL  = (float*)(arena + 36864); // [72]
  float* QMV  = (float*)(arena + 37152); // [32]
  float* KMV  = (float*)(arena + 37280); // [128] -> ends 37792

  const int flat = (int)blockIdx.x;
  const int x = flat & 7, r = flat >> 3;
  const int j = r & 31, b = r >> 5;
  const int i = x*32 + j;
  const int bi = b*NB_ + i;

  const int tid = (int)threadIdx.x;
  const int wave = tid >> 6, lane = tid & 63;
  const int lq = lane & 15, quad = lane >> 4;
  const int h = wave;
  const int start = i*32 - 48;
  u16* ATT = ATTall + h*(32*136);

  // -------- phase Z0: constants + masks --------
  if (tid < 64) WZL[tid] = lnzw[tid>>2] * Wz[tid];
  else if (tid < 68) { int hh = tid-64; float s=0.f; for (int c=0;c<16;c++) s += lnzw[c]*Wz[c*4+hh]; WZL[64+hh]=s; }
  else if (tid < 72) { int hh = tid-68; float s=0.f; for (int c=0;c<16;c++) s += lnzb[c]*Wz[c*4+hh]; WZL[68+hh]=s; }
  else if (tid >= 96 && tid < 128) QMV[tid-96] = gmask[(size_t)b*N_ + i*32 + (tid-96)];
  else if (tid >= 128) {
    int k = tid - 128;
    int raw = start + k;
    KMV[k] = (raw >= 0 && raw < N_) ? gmask[(size_t)b*N_ + raw] : 0.f;
  }
  __syncthreads();

  // -------- phase Z1: stream z coalesced, LN+proj+mask -> ZT --------
  #pragma unroll 2
  for (int it=0; it<16; ++it){
    int g = it*256 + tid;                 // q = g>>7, key = g&127
    const float* zp = gz + (size_t)bi*65536 + (size_t)g*16;
    float4 z0 = *(const float4*)(zp);
    float4 z1 = *(const float4*)(zp+4);
    float4 z2 = *(const float4*)(zp+8);
    float4 z3 = *(const float4*)(zp+12);
    int q = g >> 7, key = g & 127;
    float zv[16] = {z0.x,z0.y,z0.z,z0.w, z1.x,z1.y,z1.z,z1.w,
                    z2.x,z2.y,z2.z,z2.w, z3.x,z3.y,z3.z,z3.w};
    float sm=0.f, sq=0.f, S0=0.f, S1=0.f, S2=0.f, S3=0.f;
    #pragma unroll
    for (int c=0;c<16;c++){
      sm += zv[c]; sq = fmaf(zv[c],zv[c],sq);
      S0 = fmaf(zv[c], WZL[c*4+0], S0); S1 = fmaf(zv[c], WZL[c*4+1], S1);
      S2 = fmaf(zv[c], WZL[c*4+2], S2); S3 = fmaf(zv[c], WZL[c*4+3], S3);
    }
    float mz = sm*(1.f/16.f);
    float rz = rsqrtf(sq*(1.f/16.f) - mz*mz + EPS_);
    float mb = 1000000000.0f*(QMV[q]*KMV[key] - 1.f);
    int base = key*36 + q;
    ZT[0*4608 + base] = f2bf((S0 - mz*WZL[64])*rz + WZL[68] + mb);
    ZT[1*4608 + base] = f2bf((S1 - mz*WZL[65])*rz + WZL[69] + mb);
    ZT[2*4608 + base] = f2bf((S2 - mz*WZL[66])*rz + WZL[70] + mb);
    ZT[3*4608 + base] = f2bf((S3 - mz*WZL[67])*rz + WZL[71] + mb);
  }
  __syncthreads();

  // -------- logits: L = Q_h @ K_h^T --------
  f32x4 L[2][8];
  #pragma unroll
  for (int mt=0;mt<2;mt++) for (int nt=0;nt<8;nt++) L[mt][nt] = (f32x4)(0.f);
  {
    U16x8 aQ[2];
    #pragma unroll
    for (int mt=0;mt<2;mt++)
      aQ[mt].u4 = *(const uint4*)(Q + ((size_t)b*N_ + i*32 + mt*16 + lq)*128 + h*32 + quad*8);
    #pragma unroll
    for (int nt=0;nt<8;nt++){
      int kr = min(max(start + nt*16 + lq, 0), N_-1);
      U16x8 bk; bk.u4 = *(const uint4*)(K + ((size_t)b*N_ + kr)*128 + h*32 + quad*8);
      L[0][nt] = __builtin_amdgcn_mfma_f32_16x16x32_bf16(aQ[0].v, bk.v, L[0][nt], 0,0,0);
      L[1][nt] = __builtin_amdgcn_mfma_f32_16x16x32_bf16(aQ[1].v, bk.v, L[1][nt], 0,0,0);
    }
  }

  // -------- add bias from ZT (wave h reads plane h; 8B-aligned ushort4) --------
  #pragma unroll
  for (int nt=0;nt<8;nt++){
    #pragma unroll
    for (int mt=0;mt<2;mt++){
      ushort4 z4 = *(const ushort4*)(ZT + h*4608 + (nt*16+lq)*36 + mt*16 + quad*4);
      L[mt][nt][0] += bf2f(z4.x); L[mt][nt][1] += bf2f(z4.y);
      L[mt][nt][2] += bf2f(z4.z); L[mt][nt][3] += bf2f(z4.w);
    }
  }
  __syncthreads();   // ZT fully consumed before ATT overwrites arena (plane/region misalignment)

  // -------- softmax, write attn bf16 into per-wave ATT --------
  #pragma unroll
  for (int mt=0;mt<2;mt++){
    #pragma unroll
    for (int reg=0;reg<4;reg++){
      float mx = -3.0e38f;
      #pragma unroll
      for (int nt=0;nt<8;nt++) mx = fmaxf(mx, L[mt][nt][reg]);
      mx = fmaxf(mx, __shfl_xor(mx,1,16));
      mx = fmaxf(mx, __shfl_xor(mx,2,16));
      mx = fmaxf(mx, __shfl_xor(mx,4,16));
      mx = fmaxf(mx, __shfl_xor(mx,8,16));
      float e[8]; float s = 0.f;
      #pragma unroll
      for (int nt=0;nt<8;nt++){ e[nt] = __expf(L[mt][nt][reg]-mx); s += e[nt]; }
      s += __shfl_xor(s,1,16);
      s += __shfl_xor(s,2,16);
      s += __shfl_xor(s,4,16);
      s += __shfl_xor(s,8,16);
      float inv = 1.f/s;
      int q = mt*16 + quad*4 + reg;
      #pragma unroll
      for (int nt=0;nt<8;nt++) ATT[q*136 + nt*16 + lq] = f2bf(e[nt]*inv);
    }
  }

  // -------- o^T = V_h^T @ attn^T --------
  f32x4 O[2][2];
  O[0][0]=(f32x4)(0.f); O[0][1]=(f32x4)(0.f); O[1][0]=(f32x4)(0.f); O[1][1]=(f32x4)(0.f);
  #pragma unroll
  for (int ks=0;ks<4;ks++){
    U16x8 ba[2];
    #pragma unroll
    for (int nt=0;nt<2;nt++)
      ba[nt].u4 = *(const uint4*)(ATT + (nt*16+lq)*136 + ks*32 + quad*8);
    int kk = start + ks*32 + quad*8;
    kk = min(max(kk,0), N_-8);
    #pragma unroll
    for (int mt=0;mt<2;mt++){
      U16x8 av;
      av.u4 = *(const uint4*)(VT + ((size_t)(b*128 + h*32 + mt*16 + lq))*N_ + kk);
      O[mt][0] = __builtin_amdgcn_mfma_f32_16x16x32_bf16(av.v, ba[0].v, O[mt][0], 0,0,0);
      O[mt][1] = __builtin_amdgcn_mfma_f32_16x16x32_bf16(av.v, ba[1].v, O[mt][1], 0,0,0);
    }
  }
  __syncthreads();   // all waves done reading ATT before GO overwrites arena

  // -------- gate (row-major G), write g*o into GO --------
  #pragma unroll
  for (int mt=0;mt<2;mt++){
    #pragma unroll
    for (int nt=0;nt<2;nt++){
      int q = nt*16 + lq;
      int cb = h*32 + mt*16 + quad*4;
      ushort4 g4 = *(const ushort4*)(G + ((size_t)b*N_ + i*32 + q)*128 + cb);
      ushort4 p;
      p.x = f2bf(bf2f(g4.x)*O[mt][nt][0]); p.y = f2bf(bf2f(g4.y)*O[mt][nt][1]);
      p.z = f2bf(bf2f(g4.z)*O[mt][nt][2]); p.w = f2bf(bf2f(g4.w)*O[mt][nt][3]);
      *(ushort4*)(GO + q*136 + cb) = p;
    }
  }
  __syncthreads();

  // -------- out = sigmoid(ado) * (GO @ Wo + bo) --------
  {
    f32x4 U[2][2];
    U[0][0]=(f32x4)(0.f); U[0][1]=(f32x4)(0.f); U[1][0]=(f32x4)(0.f); U[1][1]=(f32x4)(0.f);
    #pragma unroll
    for (int ks=0;ks<4;ks++){
      U16x8 b0, b1;
      b0.u4 = *(const uint4*)(PW + (size_t)((((9*4+ks)*8) + wave*2+0)*64 + lane)*8);
      b1.u4 = *(const uint4*)(PW + (size_t)((((9*4+ks)*8) + wave*2+1)*64 + lane)*8);
      #pragma unroll
      for (int mt=0;mt<2;mt++){
        U16x8 a; a.u4 = *(const uint4*)(GO + (mt*16+lq)*136 + ks*32 + quad*8);
        U[mt][0] = __builtin_amdgcn_mfma_f32_16x16x32_bf16(a.v, b0.v, U[mt][0], 0,0,0);
        U[mt][1] = __builtin_amdgcn_mfma_f32_16x16x32_bf16(a.v, b1.v, U[mt][1], 0,0,0);
      }
    }
    const int cg0 = wave*32 + lq, cg1 = cg0 + 16;
    float b00 = bo[cg0], b01 = bo[cg1];
    #pragma unroll
    for (int mt=0;mt<2;mt++){
      #pragma unroll
      for (int reg=0;reg<4;reg++){
        int q = mt*16 + quad*4 + reg;
        size_t rowoff = ((size_t)b*N_ + i*32 + q)*128;
        float ad0 = bf2f(ADO[rowoff + cg0]);
        float ad1 = bf2f(ADO[rowoff + cg1]);
        gout[rowoff + cg0] = ad0*(U[mt][0][reg] + b00);
        gout[rowoff + cg1] = ad1*(U[mt][1][reg] + b01);
      }
    }
  }
}

// ============================ launch ============================
extern "C" void kernel_launch(void* const* d_in, const int* in_sizes, int n_in,
                              void* d_out, int out_size, void* d_ws, size_t ws_size,
                              hipStream_t stream) {
  (void)in_sizes; (void)n_in; (void)out_size; (void)ws_size;
  const float* ga    = (const float*)d_in[0];
  const float* gz    = (const float*)d_in[1];
  const float* gs    = (const float*)d_in[2];
  const float* gmask = (const float*)d_in[3];
  const float* lnsqw = (const float*)d_in[4];
  const float* Wgq   = (const float*)d_in[5];
  const float* bgq   = (const float*)d_in[6];
  const float* Wbq   = (const float*)d_in[7];
  const float* lnskw = (const float*)d_in[8];
  const float* Wgk   = (const float*)d_in[9];
  const float* bgk   = (const float*)d_in[10];
  const float* Wbk   = (const float*)d_in[11];
  const float* lnzw  = (const float*)d_in[12];
  const float* lnzb  = (const float*)d_in[13];
  const float* Wz    = (const float*)d_in[14];
  const float* Wq    = (const float*)d_in[15];
  const float* Wk    = (const float*)d_in[16];
  const float* Wv    = (const float*)d_in[17];
  const float* Wg    = (const float*)d_in[18];
  const float* bg    = (const float*)d_in[19];
  const float* Wo    = (const float*)d_in[20];
  const float* bo    = (const float*)d_in[21];
  const float* Wado  = (const float*)d_in[22];
  const float* bado  = (const float*)d_in[23];

  char* ws = (char*)d_ws;
  u16* Qb  = (u16*)(ws + 0);
  u16* Kb  = (u16*)(ws + 8388608);
  u16* VTb = (u16*)(ws + 16777216);
  u16* Gb  = (u16*)(ws + 25165824);
  u16* ADOb= (u16*)(ws + 33554432);
  u16* PW  = (u16*)(ws + 41943040);
  float* AUX = (float*)(ws + 41943040 + 327680);

  k0_prep<<<81, 256, 0, stream>>>(Wgq, Wbq, Wgk, Wbk, Wado, Wq, Wg, Wk, Wv, Wo,
                                  lnsqw, lnskw, PW, AUX);
  k1_proj<<<512, 256, 0, stream>>>(ga, gs, bgq, bgk, bg, bado, PW, AUX,
                                   Qb, Kb, VTb, Gb, ADOb);
  k2_attn<<<1024, 256, 0, stream>>>(gz, gmask, lnzw, lnzb, Wz, bo, PW,
                                    Qb, Kb, VTb, Gb, ADOb, (float*)d_out);
}